// Round 5
// baseline (180.635 us; speedup 1.0000x reference)
//
#include <hip/hip_runtime.h>

// Green-Ampt infiltration scan. B=16384 rows x T=2048 steps.
//
// R4 analysis: single-pass (1 wave/CU, 256 waves) is store-concurrency bound:
// ~1KB in-flight stores/wave * 256 waves ≈ 2.7 TB/s effective — the measured
// wall. Fix: two-pass checkpoint split.
//   Pass 1: 1 thread/row runs the F recurrence only (no outputs), storing F
//           at SEGS=8 segment boundaries into d_ws (coalesced, 512KB).
//   Pass 2: SEGS*(B/64)=2048 single-wave blocks (8 waves/CU); each recomputes
//           its 256-step segment from the checkpoint and writes all 3 output
//           streams through an LDS transpose (full 128B lines, the R4 fix).
// 8x waves -> 8x in-flight stores -> write BW ~5-6 TB/s.

#define GA_MIN_INF 0.1f
#define GA_EPS 1e-6f

typedef float f4 __attribute__((ext_vector_type(4)));

constexpr int SEGS = 8;   // time segments (checkpoints)
constexpr int TB   = 32;  // steps per store-batch in pass 2 (=128B/row/stream)
constexpr int PAD  = 36;  // LDS row pitch in floats (144B: 16B-aligned, 2-way-free)

__device__ __forceinline__ float ga_step(float& F, float Kv, float kpd,
                                         float pv, float& ro, float& cf) {
  float rF   = __builtin_amdgcn_rcpf(fmaxf(F, GA_EPS));
  float fcap = fmaxf(Kv + kpd * rF, GA_MIN_INF);
  float fact = fminf(pv, fcap);
  ro = fmaxf(pv - fact, 0.0f);
  F += fact;
  cf = F;
  return fact;
}

// ---------------- Pass 1: state-only scan, checkpoint every T/SEGS steps ----
__global__ __launch_bounds__(64, 1) void ga_pass1(
    const float* __restrict__ precip, const float* __restrict__ K,
    const float* __restrict__ psi, const float* __restrict__ dtheta,
    float* __restrict__ cp, int B, int T) {
  const int b = blockIdx.x * 64 + threadIdx.x;
  if (b >= B) return;
  const float Kv  = K[b];
  const float kpd = Kv * (psi[b] * dtheta[b]);
  const f4* __restrict__ pr = reinterpret_cast<const f4*>(precip + (size_t)b * T);

  const int nbat = T / 32;           // 32-float batches per row (64)
  const int bats_per_seg = (T / SEGS) / 32;  // 8

  float F = 0.0f;
  f4 buf[8], nxt[8];
#pragma unroll
  for (int i = 0; i < 8; ++i) buf[i] = pr[i];

  for (int bat = 0; bat < nbat; ++bat) {
    if ((bat % bats_per_seg) == 0) cp[(size_t)(bat / bats_per_seg) * B + b] = F;
    if (bat + 1 < nbat) {
#pragma unroll
      for (int i = 0; i < 8; ++i) nxt[i] = pr[(bat + 1) * 8 + i];
    }
#pragma unroll
    for (int i = 0; i < 8; ++i) {
      const f4 p = buf[i];
#pragma unroll
      for (int j = 0; j < 4; ++j) {
        float ro_, cf_;
        (void)ga_step(F, Kv, kpd, p[j], ro_, cf_);
      }
    }
#pragma unroll
    for (int i = 0; i < 8; ++i) buf[i] = nxt[i];
  }
}

// ---------------- Pass 2: per-segment recompute + transposed output ---------
__global__ __launch_bounds__(64, 1) void ga_pass2(
    const float* __restrict__ precip, const float* __restrict__ K,
    const float* __restrict__ psi, const float* __restrict__ dtheta,
    const float* __restrict__ cp, float* __restrict__ out, int B, int T) {
  __shared__ float st[64 * PAD];

  const int lane = threadIdx.x;
  const int nrg  = B / 64;
  const int rg   = blockIdx.x % nrg;
  const int seg  = blockIdx.x / nrg;
  const int rowbase = rg * 64;
  const int b = rowbase + lane;

  const float Kv  = K[b];
  const float kpd = Kv * (psi[b] * dtheta[b]);

  const int seglen = T / SEGS;           // 256
  const int tbase  = seg * seglen;
  float F = cp[(size_t)seg * B + b];

  const f4* __restrict__ pr = reinterpret_cast<const f4*>(precip + (size_t)b * T + tbase);

  const size_t BT = (size_t)B * (size_t)T;
  float* const o0 = out;
  float* const o1 = out + BT;
  float* const o2 = out + 2 * BT;

  const int orow = lane >> 3;            // 0..7
  const int ocol = (lane & 7) * 4;       // 0..28

  const int nbat = seglen / TB;          // 8

  f4 buf[8], nxt[8];
#pragma unroll
  for (int i = 0; i < 8; ++i) buf[i] = pr[i];

  for (int kb = 0; kb < nbat; ++kb) {
    if (kb + 1 < nbat) {
#pragma unroll
      for (int i = 0; i < 8; ++i) nxt[i] = pr[(kb + 1) * 8 + i];
    }

    f4 pfi[8], pro[8], pcf[8];
#pragma unroll
    for (int i = 0; i < 8; ++i) {
      const f4 p = buf[i];
#pragma unroll
      for (int j = 0; j < 4; ++j) {
        float ro_, cf_;
        float fa = ga_step(F, Kv, kpd, p[j], ro_, cf_);
        pfi[i][j] = fa; pro[i][j] = ro_; pcf[i][j] = cf_;
      }
    }

    const int tb = tbase + kb * TB;
    // Three streams through one LDS tile; single-wave block -> compiler
    // orders the aliasing ds ops via lgkmcnt, no barriers needed.
#pragma unroll
    for (int s = 0; s < 3; ++s) {
      const f4* src = (s == 0) ? pfi : (s == 1) ? pro : pcf;
      float* const dst = (s == 0) ? o0 : (s == 1) ? o1 : o2;
#pragma unroll
      for (int i = 0; i < 8; ++i)
        *reinterpret_cast<f4*>(&st[lane * PAD + i * 4]) = src[i];
#pragma unroll
      for (int g = 0; g < 8; ++g) {
        const int r = g * 8 + orow;
        f4 v = *reinterpret_cast<const f4*>(&st[r * PAD + ocol]);
        *reinterpret_cast<f4*>(dst + (size_t)(rowbase + r) * T + tb + ocol) = v;
      }
    }

#pragma unroll
    for (int i = 0; i < 8; ++i) buf[i] = nxt[i];
  }
}

// ---------------- Fallback (R4 single-pass) if ws too small ----------------
__global__ __launch_bounds__(64, 1) void ga_mono(
    const float* __restrict__ precip, const float* __restrict__ K,
    const float* __restrict__ psi, const float* __restrict__ dtheta,
    float* __restrict__ out, int B, int T) {
  __shared__ float st[64 * PAD];
  const int lane = threadIdx.x;
  const int rowbase = blockIdx.x * 64;
  const int b = rowbase + lane;
  const float Kv  = K[b];
  const float kpd = Kv * (psi[b] * dtheta[b]);
  const f4* __restrict__ pr = reinterpret_cast<const f4*>(precip + (size_t)b * T);
  const size_t BT = (size_t)B * (size_t)T;
  float* const o0 = out;
  float* const o1 = out + BT;
  float* const o2 = out + 2 * BT;
  const int orow = lane >> 3, ocol = (lane & 7) * 4;
  const int nbat = T / TB;
  float F = 0.0f;
  f4 buf[8], nxt[8];
#pragma unroll
  for (int i = 0; i < 8; ++i) buf[i] = pr[i];
  for (int kb = 0; kb < nbat; ++kb) {
    if (kb + 1 < nbat) {
#pragma unroll
      for (int i = 0; i < 8; ++i) nxt[i] = pr[(kb + 1) * 8 + i];
    }
    f4 pfi[8], pro[8], pcf[8];
#pragma unroll
    for (int i = 0; i < 8; ++i) {
      const f4 p = buf[i];
#pragma unroll
      for (int j = 0; j < 4; ++j) {
        float ro_, cf_;
        float fa = ga_step(F, Kv, kpd, p[j], ro_, cf_);
        pfi[i][j] = fa; pro[i][j] = ro_; pcf[i][j] = cf_;
      }
    }
    const int tb = kb * TB;
#pragma unroll
    for (int s = 0; s < 3; ++s) {
      const f4* src = (s == 0) ? pfi : (s == 1) ? pro : pcf;
      float* const dst = (s == 0) ? o0 : (s == 1) ? o1 : o2;
#pragma unroll
      for (int i = 0; i < 8; ++i)
        *reinterpret_cast<f4*>(&st[lane * PAD + i * 4]) = src[i];
#pragma unroll
      for (int g = 0; g < 8; ++g) {
        const int r = g * 8 + orow;
        f4 v = *reinterpret_cast<const f4*>(&st[r * PAD + ocol]);
        *reinterpret_cast<f4*>(dst + (size_t)(rowbase + r) * T + tb + ocol) = v;
      }
    }
#pragma unroll
    for (int i = 0; i < 8; ++i) buf[i] = nxt[i];
  }
}

extern "C" void kernel_launch(void* const* d_in, const int* in_sizes, int n_in,
                              void* d_out, int out_size, void* d_ws, size_t ws_size,
                              hipStream_t stream) {
  const float* precip = (const float*)d_in[0];
  const float* K      = (const float*)d_in[1];
  const float* psi    = (const float*)d_in[2];
  const float* dtheta = (const float*)d_in[3];
  float* out = (float*)d_out;

  const int B = in_sizes[1];            // K has B elements
  const int T = in_sizes[0] / B;        // precip is B*T

  const size_t cp_bytes = (size_t)SEGS * (size_t)B * sizeof(float);
  if (ws_size >= cp_bytes && (T % (SEGS * TB)) == 0) {
    float* cp = (float*)d_ws;
    ga_pass1<<<B / 64, 64, 0, stream>>>(precip, K, psi, dtheta, cp, B, T);
    ga_pass2<<<SEGS * (B / 64), 64, 0, stream>>>(precip, K, psi, dtheta, cp, out, B, T);
  } else {
    ga_mono<<<B / 64, 64, 0, stream>>>(precip, K, psi, dtheta, out, B, T);
  }
}

// Round 6
// 177.836 us; speedup vs baseline: 1.0157x; 1.0157x over previous
//
#include <hip/hip_runtime.h>

// Green-Ampt infiltration scan. B=16384 rows x T=2048 steps. Single pass.
//
// Evidence so far:
//  R1: row-major 16B/lane stores -> 1.88x HBM write amplification (345us)
//  R3: nontemporal -> 3.56x amplification (1008us): nt skips L2 combining
//  R4: LDS transpose, full 128B lines -> 176us, but writes stuck at ~3 TB/s
//  R5: 8x waves (two-pass checkpoint) -> neutral 180us. NOT concurrency-bound.
// Theory: 8KiB-strided 128B lines -> one HBM page-activate per line
// (fill kernel with contiguous addresses does 6.9 TB/s; we do ~3).
// Fix: stage 128 timesteps in LDS (99KB), flush 512B contiguous per row per
// store instruction (32 lanes x 16B), 4x longer page runs. Reads are
// L3-served (FETCH ~65MB << 128MB input), so only stores need fixing.

#define GA_MIN_INF 0.1f
#define GA_EPS 1e-6f

typedef float f4 __attribute__((ext_vector_type(4)));

constexpr int ROWS   = 64;    // rows per block (= lanes)
constexpr int TSTAGE = 128;   // timesteps staged per flush (512B/row/stream)
constexpr int PITCH  = 132;   // LDS row pitch in floats (16B-aligned, odd f4)

__global__ __launch_bounds__(64, 1) void ga_kernel(
    const float* __restrict__ precip, const float* __restrict__ K,
    const float* __restrict__ psi, const float* __restrict__ dtheta,
    float* __restrict__ out, int B, int T) {
  __shared__ float s0[ROWS * PITCH];   // infiltration
  __shared__ float s1[ROWS * PITCH];   // runoff
  __shared__ float s2[ROWS * PITCH];   // cumulative F

  const int lane = threadIdx.x;
  const int rowbase = blockIdx.x * ROWS;
  const int b = rowbase + lane;

  const float Kv  = K[b];
  const float kpd = Kv * (psi[b] * dtheta[b]);

  const f4* __restrict__ pr = reinterpret_cast<const f4*>(precip + (size_t)b * T);

  const size_t BT = (size_t)B * (size_t)T;
  float* const o0 = out;
  float* const o1 = out + BT;
  float* const o2 = out + 2 * BT;

  // Flush mapping: instr g covers rows {2g, 2g+1}; each row's 512B is
  // written by 32 lanes contiguously.
  const int fr = lane >> 5;          // 0..1 : which row of the pair
  const int fc = (lane & 31) * 4;    // float col 0,4,...,124

  const int nstage = T / TSTAGE;     // 16
  const int nsb = T / 32;            // 32-step sub-batches per row (64)
  float F = 0.0f;

  f4 buf[8], nxt[8];
#pragma unroll
  for (int i = 0; i < 8; ++i) buf[i] = pr[i];

  int sb = 0;
  for (int st = 0; st < nstage; ++st) {
    // ---- compute TSTAGE steps = 4 sub-batches of 32, results into LDS ----
#pragma unroll
    for (int q = 0; q < 4; ++q) {
      if (sb + 1 < nsb) {
#pragma unroll
        for (int i = 0; i < 8; ++i) nxt[i] = pr[(sb + 1) * 8 + i];
      }
#pragma unroll
      for (int i = 0; i < 8; ++i) {
        const f4 p = buf[i];
        f4 a, r, c;
#pragma unroll
        for (int j = 0; j < 4; ++j) {
          float rF   = __builtin_amdgcn_rcpf(fmaxf(F, GA_EPS));
          float fcap = fmaxf(Kv + kpd * rF, GA_MIN_INF);
          float fact = fminf(p[j], fcap);
          r[j] = fmaxf(p[j] - fact, 0.0f);
          F += fact;
          a[j] = fact;
          c[j] = F;
        }
        const int t0 = q * 32 + i * 4;
        *reinterpret_cast<f4*>(&s0[lane * PITCH + t0]) = a;
        *reinterpret_cast<f4*>(&s1[lane * PITCH + t0]) = r;
        *reinterpret_cast<f4*>(&s2[lane * PITCH + t0]) = c;
      }
#pragma unroll
      for (int i = 0; i < 8; ++i) buf[i] = nxt[i];
      ++sb;
    }

    // ---- flush: 32 instrs/stream; instr g = rows 2g,2g+1, 512B/row runs ----
    const int tb = st * TSTAGE;
#pragma unroll
    for (int g = 0; g < 32; ++g) {
      const int r = 2 * g + fr;
      const size_t go = (size_t)(rowbase + r) * T + tb + fc;
      const int lo = r * PITCH + fc;
      f4 v0 = *reinterpret_cast<const f4*>(&s0[lo]);
      f4 v1 = *reinterpret_cast<const f4*>(&s1[lo]);
      f4 v2 = *reinterpret_cast<const f4*>(&s2[lo]);
      *reinterpret_cast<f4*>(o0 + go) = v0;
      *reinterpret_cast<f4*>(o1 + go) = v1;
      *reinterpret_cast<f4*>(o2 + go) = v2;
    }
  }
}

// Fallback for shapes not divisible by the tiling (not hit for 16384x2048).
__global__ void ga_fallback(
    const float* __restrict__ precip, const float* __restrict__ K,
    const float* __restrict__ psi, const float* __restrict__ dtheta,
    float* __restrict__ out, int B, int T) {
  int b = blockIdx.x * blockDim.x + threadIdx.x;
  if (b >= B) return;
  const float Kv  = K[b];
  const float kpd = Kv * (psi[b] * dtheta[b]);
  const size_t BT = (size_t)B * (size_t)T;
  float F = 0.0f;
  for (int t = 0; t < T; ++t) {
    float pv   = precip[(size_t)b * T + t];
    float rF   = __builtin_amdgcn_rcpf(fmaxf(F, GA_EPS));
    float fcap = fmaxf(Kv + kpd * rF, GA_MIN_INF);
    float fact = fminf(pv, fcap);
    float ro   = fmaxf(pv - fact, 0.0f);
    F += fact;
    out[(size_t)b * T + t] = fact;
    out[BT + (size_t)b * T + t] = ro;
    out[2 * BT + (size_t)b * T + t] = F;
  }
}

extern "C" void kernel_launch(void* const* d_in, const int* in_sizes, int n_in,
                              void* d_out, int out_size, void* d_ws, size_t ws_size,
                              hipStream_t stream) {
  const float* precip = (const float*)d_in[0];
  const float* K      = (const float*)d_in[1];
  const float* psi    = (const float*)d_in[2];
  const float* dtheta = (const float*)d_in[3];
  float* out = (float*)d_out;

  const int B = in_sizes[1];            // K has B elements
  const int T = in_sizes[0] / B;        // precip is B*T

  if ((B % ROWS) == 0 && (T % TSTAGE) == 0) {
    ga_kernel<<<B / ROWS, 64, 0, stream>>>(precip, K, psi, dtheta, out, B, T);
  } else {
    ga_fallback<<<(B + 63) / 64, 64, 0, stream>>>(precip, K, psi, dtheta, out, B, T);
  }
}